// Round 1
// baseline (95.303 us; speedup 1.0000x reference)
//
#include <hip/hip_runtime.h>
#include <math.h>

#define BATCH 131072
#define EPS 1e-8f

// ws layout (floats):
// [0..255]     L0 (16x16)
// [256..511]   logw (16x16, [j][0]=0)
// [512]        alpha = logdet(L0 + I)
// [1024..66559] T table: logdet(L0[S,S]) for all 65536 masks

__global__ void prep_kernel(const float* W, const float* A, const float* Bm,
                            const float* Cm, float* ws) {
    int t = threadIdx.x;            // 256 threads
    int i = t >> 4, j = t & 15;
    float s = 0.f;
    #pragma unroll
    for (int k = 0; k < 16; ++k) {
        s += A[k * 16 + i] * A[k * 16 + j];                       // (A^T A)[i][j]
        s += Bm[i * 16 + k] * Cm[j * 16 + k]                      // (B C^T)[i][j]
           - Cm[i * 16 + k] * Bm[j * 16 + k];                     // (C B^T)[i][j]
    }
    if (i == j) s += EPS;
    ws[t] = s;

    if (t < 16) {  // log-softmax row t of W (16x15), prepend 0 column
        float row[15];
        float mx = -1e30f;
        #pragma unroll
        for (int q = 0; q < 15; ++q) { row[q] = W[t * 15 + q]; mx = fmaxf(mx, row[q]); }
        float se = 0.f;
        #pragma unroll
        for (int q = 0; q < 15; ++q) se += expf(row[q] - mx);
        float lse = mx + logf(se);
        ws[256 + t * 16 + 0] = 0.f;
        #pragma unroll
        for (int q = 0; q < 15; ++q) ws[256 + t * 16 + 1 + q] = row[q] - lse;
    }
}

// One thread per mask: register-resident fully-unrolled LU of the masked L0.
// tid==65536 computes alpha = logdet(L0 + I).
__global__ __launch_bounds__(64, 1) void table_kernel(const float* ws, float* T,
                                                      float* alphaOut) {
    __shared__ float sL0[256];
    int lt = threadIdx.x;
    #pragma unroll
    for (int q = 0; q < 4; ++q) sL0[lt * 4 + q] = ws[lt * 4 + q];
    __syncthreads();

    unsigned tid = blockIdx.x * 64u + (unsigned)lt;
    if (tid > 65536u) return;
    bool isAlpha = (tid == 65536u);
    unsigned m = isAlpha ? 0xFFFFu : tid;

    float a[16][16];
    #pragma unroll
    for (int i = 0; i < 16; ++i) {
        bool ai = (m >> i) & 1u;
        #pragma unroll
        for (int j = 0; j < 16; ++j) {
            bool aj = (m >> j) & 1u;
            float v = (ai && aj) ? sL0[i * 16 + j] : ((i == j) ? 1.f : 0.f);
            if (isAlpha && i == j) v += 1.f;   // L0 + I for the alpha entry
            a[i][j] = v;
        }
    }

    // LU without pivoting (valid: symmetric part of L0 is PD -> all pivots > 0)
    float logdet = 0.f;
    #pragma unroll
    for (int k = 0; k < 16; ++k) {
        float piv = a[k][k];
        logdet += __logf(fabsf(piv));
        float inv = 1.0f / piv;
        #pragma unroll
        for (int i2 = k + 1; i2 < 16; ++i2) {
            float f = a[i2][k] * inv;
            #pragma unroll
            for (int j2 = k + 1; j2 < 16; ++j2)
                a[i2][j2] = fmaf(-f, a[k][j2], a[i2][j2]);
        }
    }

    if (isAlpha) *alphaOut = logdet;
    else         T[tid]    = logdet;
}

__global__ __launch_bounds__(256) void main_kernel(const int4* __restrict__ x,
                                                   const float* __restrict__ ws,
                                                   float* __restrict__ out) {
    __shared__ float slw[256];
    int lt = threadIdx.x;
    slw[lt] = ws[256 + lt];
    __syncthreads();

    int b = blockIdx.x * 256 + lt;
    const int4* xb = x + (size_t)b * 16;

    float lw = 0.f;
    unsigned mask = 0;
    #pragma unroll
    for (int j = 0; j < 16; ++j) {
        int4 v = xb[j];                              // 4 bits of part j
        int idx = v.x + 2 * v.y + 4 * v.z + 8 * v.w; // 0..15
        lw += slw[j * 16 + idx];                     // logw[j][0]==0
        mask |= (idx != 0 ? 1u : 0u) << j;
    }
    float alpha = ws[512];
    out[b] = lw + ws[1024 + mask] - alpha;
}

extern "C" void kernel_launch(void* const* d_in, const int* in_sizes, int n_in,
                              void* d_out, int out_size, void* d_ws, size_t ws_size,
                              hipStream_t stream) {
    const float* W = (const float*)d_in[1];
    const float* A = (const float*)d_in[2];
    const float* B = (const float*)d_in[3];
    const float* C = (const float*)d_in[4];
    const int4*  x = (const int4*)d_in[0];
    float* ws  = (float*)d_ws;
    float* out = (float*)d_out;

    prep_kernel<<<1, 256, 0, stream>>>(W, A, B, C, ws);
    table_kernel<<<1025, 64, 0, stream>>>(ws, ws + 1024, ws + 512);
    main_kernel<<<BATCH / 256, 256, 0, stream>>>(x, ws, out);
}